// Round 10
// baseline (126.681 us; speedup 1.0000x reference)
//
#include <hip/hip_runtime.h>
#include <hip/hip_bf16.h>

namespace {

constexpr int Bn = 2, Sn = 2048, Hn = 16, Dn = 128;
constexpr int QBLK = 128;   // queries per tile
constexpr int KVBLK = 32;   // image chunk granularity (32 keys / 8 KB)
constexpr int RS = Hn * Dn; // 2048 floats
constexpr float QSCALE = 0.08838834764831845f * 1.4426950408889634f; // 1/sqrt(D)*log2(e)

// bf16 K/V images, pre-swizzled to the exact LDS chunk layout.
constexpr size_t IMG_BYTES = (size_t)Bn * Hn * 64 * 8192;   // 16 MB
constexpr size_t WS_NEED   = 2 * IMG_BYTES;                 // 32 MB (images only)

// split-path partials: per tile 2 slots x (16384 O + 128 m + 128 l -> pad 16896)
constexpr size_t PART_SLOT_F   = 16896;
constexpr size_t PART_TILE_F   = 2 * PART_SLOT_F;
constexpr size_t SPLIT_WS_NEED = 2 * IMG_BYTES + (size_t)512 * PART_TILE_F * 4; // ~98 MB

typedef __bf16 bf16x8 __attribute__((ext_vector_type(8)));
typedef float  f32x16 __attribute__((ext_vector_type(16)));

__device__ __forceinline__ f32x16 mfma32(bf16x8 a, bf16x8 b, f32x16 c) {
  return __builtin_amdgcn_mfma_f32_32x32x16_bf16(a, b, c, 0, 0, 0);
}
__device__ __forceinline__ unsigned pack2(float a, float b) {
  union { __bf16 h[2]; unsigned u; } r;
  r.h[0] = (__bf16)a; r.h[1] = (__bf16)b;
  return r.u;
}
// lane<->lane^32 exchange on the VALU pipe (T12 primitive).
__device__ __forceinline__ float pair_max(float x, int hi) {
  auto r = __builtin_amdgcn_permlane32_swap(__float_as_uint(x), __float_as_uint(x), false, false);
  const float sw = __uint_as_float(hi ? r[0] : r[1]);
  return fmaxf(x, sw);
}
__device__ __forceinline__ float pair_sum(float x, int hi) {
  auto r = __builtin_amdgcn_permlane32_swap(__float_as_uint(x), __float_as_uint(x), false, false);
  const float sw = __uint_as_float(hi ? r[0] : r[1]);
  return x + sw;
}
__device__ __forceinline__ float lane_bcast(int row, float v) {
  return __uint_as_float(__builtin_amdgcn_ds_bpermute(row * 4, __float_as_uint(v)));
}

// async 16B global->LDS DMA (linear dest: uniform lds base + lane*16)
__device__ __forceinline__ void cp16(const char* g, char* l) {
  __builtin_amdgcn_global_load_lds(
      (const __attribute__((address_space(1))) void*)g,
      (__attribute__((address_space(3))) void*)l, 16, 0, 0);
}

__device__ __forceinline__ void dma_barrier() {
  __builtin_amdgcn_sched_barrier(0);
  asm volatile("s_waitcnt vmcnt(0) lgkmcnt(0)" ::: "memory");
  __builtin_amdgcn_s_barrier();
  __builtin_amdgcn_sched_barrier(0);
}

// ============================================================================
// Pre-pass: fp32 K/V -> bf16 images in the EXACT swizzled LDS chunk layout.
// (verbatim, verified)
// ============================================================================
__global__ __launch_bounds__(256)
void prep_kv(const float* __restrict__ K, const float* __restrict__ V,
             __bf16* __restrict__ KI, __bf16* __restrict__ VI)
{
  const int gid  = (int)blockIdx.x * 256 + (int)threadIdx.x; // 0..2M
  const int half = gid >> 20;              // 0=K, 1=V
  const int id   = gid & ((1 << 20) - 1);  // 0..1M
  const int chunk = id >> 9;               // 0..2047
  const int rem   = id & 511;
  const int bh = chunk >> 6, c = chunk & 63;
  const int b = bh >> 4, h = bh & 15;
  if (half == 0) {
    const int key = rem >> 4, dblk = rem & 15;
    const float* src = K + ((size_t)b * Sn + (size_t)c * 32 + key) * RS + h * Dn + dblk * 8;
    float4 a  = *(const float4*)src;
    float4 c2 = *(const float4*)(src + 4);
    bf16x8 f;
    f[0] = (__bf16)a.x;  f[1] = (__bf16)a.y;  f[2] = (__bf16)a.z;  f[3] = (__bf16)a.w;
    f[4] = (__bf16)c2.x; f[5] = (__bf16)c2.y; f[6] = (__bf16)c2.z; f[7] = (__bf16)c2.w;
    char* dst = (char*)KI + (size_t)chunk * 8192 + ((key * 256 + dblk * 16) ^ ((key & 7) << 4));
    *(bf16x8*)dst = f;
  } else {
    const int d = rem >> 2, koct = rem & 3;
    const float* src = V + ((size_t)b * Sn + (size_t)c * 32 + koct * 8) * RS + h * Dn + d;
    bf16x8 f;
#pragma unroll
    for (int j = 0; j < 8; ++j) f[j] = (__bf16)src[(size_t)j * RS];
    const int off = (d * 64 + koct * 16) ^ ((d & 3) << 4) ^ (((d >> 3) & 1) << 6);
    *(bf16x8*)((char*)VI + (size_t)chunk * 8192 + off) = f;
  }
}

// ============================================================================
// fa_split: 512 blocks x 512 threads, 64 KB LDS -> 2 blocks/CU with IDENTICAL
// 17-superstep lifetimes (R8 measured 1.84 us/superstep-exec at sustained 16
// waves vs ~3.0 solo). R4's verified split-KV geometry: tile qt splits at
// 64*(qt+1) keys; block X = L(15-p)+U(p), block Y = U(15-p)+L(p), both 17.
// Co-resident (bid,bid+256): same head/pair, roles swapped. Inner loop =
// verified R6 pipelined DMA (K ring-4, V ring-4 by chunk&3). NO spin/flags
// (R4's failure): both roles write unnormalized (O,m,l) partials to ws;
// fa_merge (stream-ordered) combines.
// ============================================================================
__global__ __launch_bounds__(512)
void fa_split(const float* __restrict__ Q, const __bf16* __restrict__ KI,
              const __bf16* __restrict__ VI, float* __restrict__ WP)
{
  __shared__ __align__(16) __bf16 Klds[4][4096]; // 32 KB, slot = chunk & 3
  __shared__ __align__(16) __bf16 Vt[4][4096];   // 32 KB, slot = chunk & 3

  const int tid  = threadIdx.x;
  const int lane = tid & 63;
  const int wave = tid >> 6;
  const int col  = lane & 31;
  const int hi   = lane >> 5;
  const int grp  = wave >> 2;   // 0: even chunks, 1: odd chunks
  const int wq   = wave & 3;

  const int xcd  = (int)blockIdx.x & 7;
  const int s    = (int)blockIdx.x >> 3;    // 0..63
  const int hidx = xcd * 4 + (s & 3);       // 0..31
  const int b    = hidx >> 4, h = hidx & 15;
  const int pr   = (s >> 2) & 7;            // pair 0..7
  const int role = (s >> 2) >> 3;           // 0 / 1
  const size_t base = ((size_t)b * Sn) * RS + (size_t)h * Dn;

  const char* KIc = (const char*)KI + (size_t)hidx * 64 * 8192;
  const char* VIc = (const char*)VI + (size_t)hidx * 64 * 8192;

  // staging roles: waves 0-3 stage K (2 chunks), 4-7 stage V (2 chunks).
  const int sr = wave >> 1;           // 0..3
  const int hb = (wave & 1) * 4096;   // byte half of an 8 KB chunk
  auto stageK2 = [&](int ss) {        // chunks 2ss, 2ss+1
    if (sr < 2) {
      const int ck = 2 * ss + sr;
      const char* g = KIc + (size_t)ck * 8192 + hb;
      char* l = (char*)&Klds[ck & 3][0] + hb;
#pragma unroll
      for (int i = 0; i < 4; ++i) cp16(g + i * 1024 + lane * 16, l + i * 1024);
    }
  };
  auto stageV2 = [&](int ss) {
    if (sr >= 2) {
      const int cv = 2 * ss + (sr - 2);
      const char* g = VIc + (size_t)cv * 8192 + hb;
      char* l = (char*)&Vt[cv & 3][0] + hb;
#pragma unroll
      for (int i = 0; i < 4; ++i) cp16(g + i * 1024 + lane * 16, l + i * 1024);
    }
  };

  const int cswz = (col & 7) << 4;
  const int vswz = ((col & 3) << 4) ^ (((col >> 3) & 1) << 6);

#pragma unroll 1
  for (int half = 0; half < 2; ++half) {
    const int qt    = half ? pr : (15 - pr);
    const int Th    = half ? (pr + 1) : (16 - pr);  // supersteps in this half
    const int lower = (role == half);               // which KV half this block takes
    const int t0 = lower ? 0 : Th;
    const int t1 = t0 + Th;
    const int q0w = qt * QBLK + wq * 32;

    // ---- Q fragments, scaled ----
    bf16x8 qf[8];
    {
      const float* qp = Q + base + (size_t)(q0w + col) * RS + hi * 8;
#pragma unroll
      for (int kk = 0; kk < 8; ++kk) {
        float4 a = *(const float4*)(qp + kk * 16);
        float4 c2 = *(const float4*)(qp + kk * 16 + 4);
        bf16x8 f;
        f[0] = (__bf16)(a.x * QSCALE);  f[1] = (__bf16)(a.y * QSCALE);
        f[2] = (__bf16)(a.z * QSCALE);  f[3] = (__bf16)(a.w * QSCALE);
        f[4] = (__bf16)(c2.x * QSCALE); f[5] = (__bf16)(c2.y * QSCALE);
        f[6] = (__bf16)(c2.z * QSCALE); f[7] = (__bf16)(c2.w * QSCALE);
        qf[kk] = f;
      }
    }

    f32x16 o0 = {}, o1 = {}, o2 = {}, o3 = {};
    float m = -1e30f, l = 0.f;

    // ---- prologue: DMA K(t0),V(t0),K(t0+1); wait; S(t0); fence ----
    stageK2(t0);
    stageV2(t0);
    if (t0 + 1 < t1) stageK2(t0 + 1);
    dma_barrier();

    f32x16 st_cur = {};
    if ((2 * t0 + grp) * KVBLK <= q0w + 31) {
      const char* kb = (const char*)&Klds[(2 * t0 + grp) & 3][0];
      __builtin_amdgcn_s_setprio(1);
#pragma unroll
      for (int kk = 0; kk < 8; ++kk) {
        bf16x8 ka = *(const bf16x8*)(kb + ((col * 256 + kk * 32 + hi * 16) ^ cswz));
        st_cur = mfma32(ka, qf[kk], st_cur);
      }
      __builtin_amdgcn_s_setprio(0);
    }
    dma_barrier();   // fence S(t0) slot reads vs iter-t0 stageK2(t0+2)

#pragma unroll 1
    for (int t = t0; t < t1; ++t) {
      // ---- issue next DMAs first (slots' reads drained at iter t-1 barrier) ----
      if (t + 2 < t1) stageK2(t + 2);
      if (t + 1 < t1) stageV2(t + 1);

      // ---- QK^T(t+1) on the MFMA pipe ----
      f32x16 stn = {};
      const int icn = 2 * (t + 1) + grp;
      if (t + 1 < t1 && icn * KVBLK <= q0w + 31) {
        const char* kb = (const char*)&Klds[icn & 3][0];
        __builtin_amdgcn_s_setprio(1);
#pragma unroll
        for (int kk = 0; kk < 8; ++kk) {
          bf16x8 ka = *(const bf16x8*)(kb + ((col * 256 + kk * 32 + hi * 16) ^ cswz));
          stn = mfma32(ka, qf[kk], stn);
        }
        __builtin_amdgcn_s_setprio(0);
      }

      // ---- finish chunk t: mask, softmax, repack, PV ----
      const int kv0 = (2 * t + grp) * KVBLK;
      if (kv0 <= q0w + 31) {
        if (kv0 + KVBLK - 1 > q0w) {
          const int qk = q0w + col - kv0;
#pragma unroll
          for (int r = 0; r < 16; ++r) {
            const int krow = (r & 3) + 8 * (r >> 2) + 4 * hi;
            st_cur[r] = (krow <= qk) ? st_cur[r] : -1e30f;
          }
        }

        float t8[8];
#pragma unroll
        for (int r = 0; r < 8; ++r) t8[r] = fmaxf(st_cur[r], st_cur[r + 8]);
#pragma unroll
        for (int r = 0; r < 4; ++r) t8[r] = fmaxf(t8[r], t8[r + 4]);
        const float pmax = pair_max(fmaxf(fmaxf(t8[0], t8[1]), fmaxf(t8[2], t8[3])), hi);

        if (!__all(pmax <= m + 11.0f)) {   // T13 defer-max
          const float mnew = fmaxf(m, pmax);
          const float al = __builtin_amdgcn_exp2f(m - mnew);
          m = mnew;
          l *= al;
#pragma unroll
          for (int r = 0; r < 16; ++r) {
            const int row = (r & 3) + 8 * (r >> 2) + 4 * hi;
            const float ar = lane_bcast(row, al);
            o0[r] *= ar; o1[r] *= ar; o2[r] *= ar; o3[r] *= ar;
          }
        }

        float s4[4] = {0.f, 0.f, 0.f, 0.f};
#pragma unroll
        for (int r = 0; r < 16; ++r) {
          st_cur[r] = __builtin_amdgcn_exp2f(st_cur[r] - m);
          s4[r & 3] += st_cur[r];
        }
        l += pair_sum((s4[0] + s4[1]) + (s4[2] + s4[3]), hi);

        // P -> A-fragments via 4 permlane32_swap
        unsigned cw[8];
#pragma unroll
        for (int i = 0; i < 8; ++i) cw[i] = pack2(st_cur[2 * i], st_cur[2 * i + 1]);
        union { unsigned u[4]; bf16x8 v; } pa0, pa1;
        {
          auto s02 = __builtin_amdgcn_permlane32_swap(cw[0], cw[2], false, false);
          auto s13 = __builtin_amdgcn_permlane32_swap(cw[1], cw[3], false, false);
          auto s46 = __builtin_amdgcn_permlane32_swap(cw[4], cw[6], false, false);
          auto s57 = __builtin_amdgcn_permlane32_swap(cw[5], cw[7], false, false);
          pa0.u[0] = s02[0]; pa0.u[2] = s02[1];
          pa0.u[1] = s13[0]; pa0.u[3] = s13[1];
          pa1.u[0] = s46[0]; pa1.u[2] = s46[1];
          pa1.u[1] = s57[0]; pa1.u[3] = s57[1];
        }

        const char* vb = (const char*)&Vt[(2 * t + grp) & 3][0];
        __builtin_amdgcn_s_setprio(1);
#pragma unroll
        for (int ks = 0; ks < 2; ++ks) {
          const bf16x8 pa = ks ? pa1.v : pa0.v;
#define PV_STEP(ovar, dt) { \
          bf16x8 vf = *(const bf16x8*)(vb + ((((dt)*32 + col) * 64 + ks * 32 + hi * 16) ^ vswz)); \
          ovar = mfma32(pa, vf, ovar); }
          PV_STEP(o0, 0) PV_STEP(o1, 1) PV_STEP(o2, 2) PV_STEP(o3, 3)
#undef PV_STEP
        }
        __builtin_amdgcn_s_setprio(0);
      }
      dma_barrier();
      st_cur = stn;
    }

    // ---- merge grp1 -> grp0 (LDS scratch over K/V rings), keep (o,m,l) ----
    float* ob  = reinterpret_cast<float*>(&Klds[0][0]);   // 8192 floats (32 KB)
    float* mlb = reinterpret_cast<float*>(&Vt[0][0]);
    if (grp == 1) {
      mlb[wq * 128 + lane] = m;
      mlb[wq * 128 + 64 + lane] = l;
#pragma unroll
      for (int r = 0; r < 16; ++r) {
        ob[wq * 1024 + r * 64 + lane] = o0[r];
        ob[4096 + wq * 1024 + r * 64 + lane] = o1[r];
      }
    }
    __syncthreads();
    float f0 = 1.f, f1 = 0.f;
    if (grp == 0) {
      const float m1 = mlb[wq * 128 + lane];
      const float l1 = mlb[wq * 128 + 64 + lane];
      const float mS = fmaxf(m, m1);
      f0 = __builtin_amdgcn_exp2f(m - mS);
      f1 = __builtin_amdgcn_exp2f(m1 - mS);
      m = mS;
      l = l * f0 + l1 * f1;
#pragma unroll
      for (int r = 0; r < 16; ++r) {
        const int row = (r & 3) + 8 * (r >> 2) + 4 * hi;
        const float a0 = lane_bcast(row, f0), a1 = lane_bcast(row, f1);
        o0[r] = o0[r] * a0 + ob[wq * 1024 + r * 64 + lane] * a1;
        o1[r] = o1[r] * a0 + ob[4096 + wq * 1024 + r * 64 + lane] * a1;
      }
    }
    __syncthreads();
    if (grp == 1) {
#pragma unroll
      for (int r = 0; r < 16; ++r) {
        ob[wq * 1024 + r * 64 + lane] = o2[r];
        ob[4096 + wq * 1024 + r * 64 + lane] = o3[r];
      }
    }
    __syncthreads();

    // ---- write unnormalized partial (O, m, l) to workspace; NO handshake ----
    const int tix = hidx * 16 + qt;
    float* W = WP + (size_t)tix * PART_TILE_F + (lower ? 0 : PART_SLOT_F);
    if (grp == 0) {
#pragma unroll
      for (int r = 0; r < 16; ++r) {
        const int row = (r & 3) + 8 * (r >> 2) + 4 * hi;
        const float a0 = lane_bcast(row, f0), a1 = lane_bcast(row, f1);
        o2[r] = o2[r] * a0 + ob[wq * 1024 + r * 64 + lane] * a1;
        o3[r] = o3[r] * a0 + ob[4096 + wq * 1024 + r * 64 + lane] * a1;
        float* wp = W + (size_t)(wq * 32 + row) * 128 + col;
        wp[0]  = o0[r];
        wp[32] = o1[r];
        wp[64] = o2[r];
        wp[96] = o3[r];
      }
      if (hi == 0) {
        W[16384 + wq * 32 + col] = m;
        W[16512 + wq * 32 + col] = l;
      }
    }
    __syncthreads();   // protect LDS scratch/rings before next half's staging
  }
}

// ============================================================================
// fa_merge: per tile, combine the two unnormalized partials and store O.
// 512 blocks x 256 threads; pure streaming (~100 MB).
// ============================================================================
__global__ __launch_bounds__(256)
void fa_merge(const float* __restrict__ WP, float* __restrict__ O)
{
  const int tix  = (int)blockIdx.x;       // 0..511
  const int hidx = tix >> 4, qt = tix & 15;
  const int b = hidx >> 4, h = hidx & 15;
  const size_t base = ((size_t)b * Sn) * RS + (size_t)h * Dn;
  const int q0 = qt * QBLK;
  const float* W0 = WP + (size_t)tix * PART_TILE_F;
  const float* W1 = W0 + PART_SLOT_F;

  __shared__ float a0s[128], a1s[128];
  const int t = threadIdx.x;
  if (t < 128) {
    const float m0 = W0[16384 + t], l0 = W0[16512 + t];
    const float m1 = W1[16384 + t], l1 = W1[16512 + t];
    const float M  = fmaxf(m0, m1);
    const float c0 = __builtin_amdgcn_exp2f(m0 - M);
    const float c1 = __builtin_amdgcn_exp2f(m1 - M);
    const float li = 1.0f / (l0 * c0 + l1 * c1);
    a0s[t] = c0 * li;
    a1s[t] = c1 * li;
  }
  __syncthreads();

#pragma unroll
  for (int i = 0; i < 16; ++i) {
    const int fl   = t + 256 * i;       // float4 index 0..4095
    const int elem = fl * 4;
    const int r    = elem >> 7;
    const int d    = elem & 127;
    const float4 p0 = *(const float4*)(W0 + elem);
    const float4 p1 = *(const float4*)(W1 + elem);
    const float a0 = a0s[r], a1 = a1s[r];
    float4 o;
    o.x = p0.x * a0 + p1.x * a1;
    o.y = p0.y * a0 + p1.y * a1;
    o.z = p0.z * a0 + p1.z * a1;
    o.w = p0.w * a0 + p1.w * a1;
    *(float4*)(O + base + (size_t)(q0 + r) * RS + d) = o;
  }
}

// ============================================================================
// Fallback (ws < SPLIT_WS_NEED): verbatim R7 kernel — session best, 97.3 us.
// 256 blocks (1/CU, 128 KB LDS) x 512 threads; 128-key supersteps; block p
// runs tiles (15-p) then (p): uniform 17 double-supersteps.
// ============================================================================
__global__ __launch_bounds__(512)
void fa_fwd_pair(const float* __restrict__ Q, const __bf16* __restrict__ KI,
                 const __bf16* __restrict__ VI, float* __restrict__ O)
{
  __shared__ __align__(16) __bf16 Klds[8][4096]; // 64 KB, slot = chunk32 & 7
  __shared__ __align__(16) __bf16 Vt[8][4096];   // 64 KB, slot = chunk32 & 7

  const int tid  = threadIdx.x;
  const int lane = tid & 63;
  const int wave = tid >> 6;
  const int col  = lane & 31;
  const int hi   = lane >> 5;
  const int grp  = wave >> 2;
  const int wq   = wave & 3;

  const int xcd  = (int)blockIdx.x & 7;
  const int s    = (int)blockIdx.x >> 3;    // 0..31
  const int hidx = xcd * 4 + (s & 3);
  const int b    = hidx >> 4, h = hidx & 15;
  const int p    = s >> 2;
  const size_t base = ((size_t)b * Sn) * RS + (size_t)h * Dn;

  const char* KIc = (const char*)KI + (size_t)hidx * 64 * 8192;
  const char* VIc = (const char*)VI + (size_t)hidx * 64 * 8192;

  auto stageKc = [&](int cc) {
    const char* g = KIc + (size_t)cc * 8192 + lane * 16;
    char* l = (char*)&Klds[cc & 7][0];
#pragma unroll
    for (int i = 0; i < 8; ++i) cp16(g + i * 1024, l + i * 1024);
  };
  auto stageVc = [&](int cc) {
    const char* g = VIc + (size_t)cc * 8192 + lane * 16;
    char* l = (char*)&Vt[cc & 7][0];
#pragma unroll
    for (int i = 0; i < 8; ++i) cp16(g + i * 1024, l + i * 1024);
  };

  const int cswz = (col & 7) << 4;
  const int vswz = ((col & 3) << 4) ^ (((col >> 3) & 1) << 6);

#define QK8(kbp, acc) { \
  __builtin_amdgcn_s_setprio(1); \
  _Pragma("unroll") \
  for (int kk = 0; kk < 8; ++kk) { \
    bf16x8 ka = *(const bf16x8*)((kbp) + ((col * 256 + kk * 32 + hi * 16) ^ cswz)); \
    acc = mfma32(ka, qf[kk], acc); \
  } \
  __builtin_amdgcn_s_setprio(0); }

#pragma unroll 1
  for (int tp = 0; tp < 2; ++tp) {
    const int qt  = tp ? p : (15 - p);
    const int q0w = qt * QBLK + wq * 32;
    const int T   = qt + 1;

    bf16x8 qf[8];
    {
      const float* qp = Q + base + (size_t)(q0w + col) * RS + hi * 8;
#pragma unroll
      for (int kk = 0; kk < 8; ++kk) {
        float4 a = *(const float4*)(qp + kk * 16);
        float4 c2 = *(const float4*)(qp + kk * 16 + 4);
        bf16x8 f;
        f[0] = (__bf16)(a.x * QSCALE);  f[1] = (__bf16)(a.y * QSCALE);
        f[2] = (__bf16)(a.z * QSCALE);  f[3] = (__bf16)(a.w * QSCALE);
        f[4] = (__bf16)(c2.x * QSCALE); f[5] = (__bf16)(c2.y * QSCALE);
        f[6] = (__bf16)(c2.z * QSCALE); f[7] = (__bf16)(c2.w * QSCALE);
        qf[kk] = f;
      }
    }

    f32x16 o0 = {}, o1 = {}, o2 = {}, o3 = {};
    float m = -1e30f, l = 0.f;

    if (wave < 4) stageKc(wave); else stageVc(wave - 4);
    if (T > 1 && wave < 4) stageKc(4 + wave);
    dma_barrier();

    f32x16 sc0 = {}, sc1 = {};
    {
      const int cc = 2 * grp;
      if (cc * 32 <= q0w + 31) {
        const char* kb = (const char*)&Klds[cc][0];
        QK8(kb, sc0)
        if ((cc + 1) * 32 <= q0w + 31) {
          const char* kb1 = (const char*)&Klds[cc + 1][0];
          QK8(kb1, sc1)
        }
      }
    }
    dma_barrier();

#pragma unroll 1
    for (int t = 0; t < T; ++t) {
      if (t + 2 < T && wave < 4) stageKc(4 * (t + 2) + wave);
      if (t + 1 < T && wave >= 4) stageVc(4 * (t + 1) + (wave - 4));

      f32x16 sn0 = {}, sn1 = {};
      if (t + 1 < T) {
        const int cc = 4 * (t + 1) + 2 * grp;
        if (cc * 32 <= q0w + 31) {
          const char* kb = (const char*)&Klds[cc & 7][0];
          QK8(kb, sn0)
          if ((cc + 1) * 32 <= q0w + 31) {
            const char* kb1 = (const char*)&Klds[(cc + 1) & 7][0];
            QK8(kb1, sn1)
          }
        }
      }

      const int cc0 = 4 * t + 2 * grp;
      const int kv0 = cc0 * 32;
      if (kv0 <= q0w + 31) {
        const bool v1 = (kv0 + 32) <= q0w + 31;

        if (kv0 + 31 > q0w) {
          const int qk = q0w + col - kv0;
#pragma unroll
          for (int r = 0; r < 16; ++r) {
            const int krow = (r & 3) + 8 * (r >> 2) + 4 * hi;
            sc0[r] = (krow <= qk) ? sc0[r] : -1e30f;
          }
        }
        if (v1 && kv0 + 63 > q0w) {
          const int qk1 = q0w + col - (kv0 + 32);
#pragma unroll
          for (int r = 0; r < 16; ++r) {
            const int krow = (r & 3) + 8 * (r >> 2) + 4 * hi;
            sc1[r] = (krow <= qk1) ? sc1[r] : -1e30f;
          }
        }

        float t8[8];
#pragma unroll
        for (int r = 0; r < 8; ++r) t8[r] = fmaxf(sc0[r], sc0[r + 8]);
        if (v1) {
#pragma unroll
          for (int r = 0; r < 8; ++r) t8[r] = fmaxf(t8[r], fmaxf(sc1[r], sc1[r + 8]));
        }
#pragma unroll
        for (int r = 0; r < 4; ++r) t8[r] = fmaxf(t8[r], t8[r + 4]);
        const float pmax = pair_max(fmaxf(fmaxf(t8[0], t8[1]), fmaxf(t8[2], t8[3])), hi);

        if (!__all(pmax <= m + 11.0f)) {
          const float mnew = fmaxf(m, pmax);
          const float al = __builtin_amdgcn_exp2f(m - mnew);
          m = mnew;
          l *= al;
#pragma unroll
          for (int r = 0; r < 16; ++r) {
            const int row = (r & 3) + 8 * (r >> 2) + 4 * hi;
            const float ar = lane_bcast(row, al);
            o0[r] *= ar; o1[r] *= ar; o2[r] *= ar; o3[r] *= ar;
          }
        }

        float s4[4] = {0.f, 0.f, 0.f, 0.f};
#pragma unroll
        for (int r = 0; r < 16; ++r) {
          sc0[r] = __builtin_amdgcn_exp2f(sc0[r] - m);
          s4[r & 3] += sc0[r];
        }
        if (v1) {
#pragma unroll
          for (int r = 0; r < 16; ++r) {
            sc1[r] = __builtin_amdgcn_exp2f(sc1[r] - m);
            s4[r & 3] += sc1[r];
          }
        }
        l += pair_sum((s4[0] + s4[1]) + (s4[2] + s4[3]), hi);

        union { unsigned u[4]; bf16x8 v; } pa0, pa1, pb0, pb1;
        {
          unsigned cw[8];
#pragma unroll
          for (int i = 0; i < 8; ++i) cw[i] = pack2(sc0[2 * i], sc0[2 * i + 1]);
          auto s02 = __builtin_amdgcn_permlane32_swap(cw[0], cw[2], false, false);
          auto s13 = __builtin_amdgcn_permlane32_swap(cw[1], cw[3], false, false);
          auto s46 = __builtin_amdgcn_permlane32_swap(cw[4], cw[6], false, false);
          auto s57 = __builtin_amdgcn_permlane32_swap(cw[5], cw[7], false, false);
          pa0.u[0] = s02[0]; pa0.u[2] = s02[1];
          pa0.u[1] = s13[0]; pa0.u[3] = s13[1];
          pa1.u[0] = s46[0]; pa1.u[2] = s46[1];
          pa1.u[1] = s57[0]; pa1.u[3] = s57[1];
        }
        if (v1) {
          unsigned cw[8];
#pragma unroll
          for (int i = 0; i < 8; ++i) cw[i] = pack2(sc1[2 * i], sc1[2 * i + 1]);
          auto s02 = __builtin_amdgcn_permlane32_swap(cw[0], cw[2], false, false);
          auto s13 = __builtin_amdgcn_permlane32_swap(cw[1], cw[3], false, false);
          auto s46 = __builtin_amdgcn_permlane32_swap(cw[4], cw[6], false, false);
          auto s57 = __builtin_amdgcn_permlane32_swap(cw[5], cw[7], false, false);
          pb0.u[0] = s02[0]; pb0.u[2] = s02[1];
          pb0.u[1] = s13[0]; pb0.u[3] = s13[1];
          pb1.u[0] = s46[0]; pb1.u[2] = s46[1];
          pb1.u[1] = s57[0]; pb1.u[3] = s57[1];
        }

        const char* vb0 = (const char*)&Vt[cc0 & 7][0];
        const char* vb1 = (const char*)&Vt[(cc0 + 1) & 7][0];
        __builtin_amdgcn_s_setprio(1);
#pragma unroll
        for (int ks = 0; ks < 2; ++ks) {
          const bf16x8 pa = ks ? pa1.v : pa0.v;
#define PV_STEP(ovar, dt, vbp) { \
          bf16x8 vf = *(const bf16x8*)((vbp) + ((((dt)*32 + col) * 64 + ks * 32 + hi * 16) ^ vswz)); \
          ovar = mfma32(pa, vf, ovar); }
          PV_STEP(o0, 0, vb0) PV_STEP(o1, 1, vb0) PV_STEP(o2, 2, vb0) PV_STEP(o3, 3, vb0)
        }
        if (v1) {
#pragma unroll
          for (int ks = 0; ks < 2; ++ks) {
            const bf16x8 pa = ks ? pb1.v : pb0.v;
            PV_STEP(o0, 0, vb1) PV_STEP(o1, 1, vb1) PV_STEP(o2, 2, vb1) PV_STEP(o3, 3, vb1)
#undef PV_STEP
          }
        }
        __builtin_amdgcn_s_setprio(0);
      }
      dma_barrier();
      sc0 = sn0; sc1 = sn1;
    }

    float* ob  = reinterpret_cast<float*>(&Klds[0][0]);
    float* mlb = reinterpret_cast<float*>(&Vt[0][0]);
    float f0 = 1.f, f1 = 0.f;
    {
      const int src = grp & 1;
      float* obr = ob  + (grp >> 1) * 8192;
      float* mlr = mlb + (grp >> 1) * 512;
      if (src) {
        mlr[wq * 128 + lane] = m;
        mlr[wq * 128 + 64 + lane] = l;
#pragma unroll
        for (int r = 0; r < 16; ++r) {
          obr[wq * 1024 + r * 64 + lane] = o0[r];
          obr[4096 + wq * 1024 + r * 64 + lane] = o1[r];
        }
      }
      __syncthreads();
      if (!src) {
        const float m1 = mlr[wq * 128 + lane];
        const float l1 = mlr[wq * 128 + 64 + lane];
        const float mS = fmaxf(m, m1);
        f0 = __builtin_amdgcn_exp2f(m - mS);
        f1 = __builtin_amdgcn_exp2f(m1 - mS);
        m = mS;
        l = l * f0 + l1 * f1;
#pragma unroll
        for (int r = 0; r < 16; ++r) {
          const int row = (r & 3) + 8 * (r >> 2) + 4 * hi;
          const float a0 = lane_bcast(row, f0), a1 = lane_bcast(row, f1);
          o0[r] = o0[r] * a0 + obr[wq * 1024 + r * 64 + lane] * a1;
          o1[r] = o1[r] * a0 + obr[4096 + wq * 1024 + r * 64 + lane] * a1;
        }
      }
      __syncthreads();
      if (src) {
#pragma unroll
        for (int r = 0; r < 16; ++r) {
          obr[wq * 1024 + r * 64 + lane] = o2[r];
          obr[4096 + wq * 1024 + r * 64 + lane] = o3[r];
        }
      }
      __syncthreads();
      if (!src) {
#pragma unroll
        for (int r = 0; r < 16; ++r) {
          const int row = (r & 3) + 8 * (r >> 2) + 4 * hi;
          const float a0 = lane_bcast(row, f0), a1 = lane_bcast(row, f1);
          o2[r] = o2[r] * a0 + obr[wq * 1024 + r * 64 + lane] * a1;
          o3[r] = o3[r] * a0 + obr[4096 + wq * 1024 + r * 64 + lane] * a1;
        }
      }
      __syncthreads();
    }
    {
      if (grp == 2) {
        mlb[wq * 128 + lane] = m;
        mlb[wq * 128 + 64 + lane] = l;
#pragma unroll
        for (int r = 0; r < 16; ++r) {
          ob[wq * 1024 + r * 64 + lane] = o0[r];
          ob[4096 + wq * 1024 + r * 64 + lane] = o1[r];
        }
      }
      __syncthreads();
      if (grp == 0) {
        const float m1 = mlb[wq * 128 + lane];
        const float l1 = mlb[wq * 128 + 64 + lane];
        const float mS = fmaxf(m, m1);
        f0 = __builtin_amdgcn_exp2f(m - mS);
        f1 = __builtin_amdgcn_exp2f(m1 - mS);
        l = l * f0 + l1 * f1;
#pragma unroll
        for (int r = 0; r < 16; ++r) {
          const int row = (r & 3) + 8 * (r >> 2) + 4 * hi;
          const float a0 = lane_bcast(row, f0), a1 = lane_bcast(row, f1);
          o0[r] = o0[r] * a0 + ob[wq * 1024 + r * 64 + lane] * a1;
          o1[r] = o1[r] * a0 + ob[4096 + wq * 1024 + r * 64 + lane] * a1;
        }
      }
      __syncthreads();
      if (grp == 2) {
#pragma unroll
        for (int r = 0; r < 16; ++r) {
          ob[wq * 1024 + r * 64 + lane] = o2[r];
          ob[4096 + wq * 1024 + r * 64 + lane] = o3[r];
        }
      }
      __syncthreads();
      if (grp == 0) {
#pragma unroll
        for (int r = 0; r < 16; ++r) {
          const int row = (r & 3) + 8 * (r >> 2) + 4 * hi;
          const float a0 = lane_bcast(row, f0), a1 = lane_bcast(row, f1);
          o2[r] = o2[r] * a0 + ob[wq * 1024 + r * 64 + lane] * a1;
          o3[r] = o3[r] * a0 + ob[4096 + wq * 1024 + r * 64 + lane] * a1;
        }
        const float linv = 1.0f / l;
#pragma unroll
        for (int r = 0; r < 16; ++r) {
          const int row = (r & 3) + 8 * (r >> 2) + 4 * hi;
          const float lr = lane_bcast(row, linv);
          float* op = O + base + (size_t)(q0w + row) * RS + col;
          op[0]  = o0[r] * lr;
          op[32] = o1[r] * lr;
          op[64] = o2[r] * lr;
          op[96] = o3[r] * lr;
        }
      }
    }
    __syncthreads();
  }
#undef QK8
}

} // namespace

extern "C" void kernel_launch(void* const* d_in, const int* /*in_sizes*/, int /*n_in*/,
                              void* d_out, int /*out_size*/, void* d_ws, size_t ws_size,
                              hipStream_t stream) {
  const float* q = (const float*)d_in[0];
  const float* k = (const float*)d_in[1];
  const float* v = (const float*)d_in[2];
  float* o = (float*)d_out;
  __bf16* ki = (__bf16*)d_ws;
  __bf16* vi = (__bf16*)((char*)d_ws + IMG_BYTES);
  if (d_ws != nullptr && ws_size >= SPLIT_WS_NEED) {
    float* wp = (float*)((char*)d_ws + 2 * IMG_BYTES);
    hipLaunchKernelGGL(prep_kv, dim3(8192), dim3(256), 0, stream, k, v, ki, vi);
    hipLaunchKernelGGL(fa_split, dim3(512), dim3(512), 0, stream, q, ki, vi, wp);
    hipLaunchKernelGGL(fa_merge, dim3(512), dim3(256), 0, stream, wp, o);
  } else {
    // ws >= 32 MB proven on this harness (rounds 6-9 ran the image path)
    hipLaunchKernelGGL(prep_kv, dim3(8192), dim3(256), 0, stream, k, v, ki, vi);
    hipLaunchKernelGGL(fa_fwd_pair, dim3(256), dim3(512), 0, stream, q, ki, vi, o);
  }
}